// Round 1
// baseline (263.845 us; speedup 1.0000x reference)
//
#include <hip/hip_runtime.h>
#include <hip/hip_bf16.h>
#include <math.h>

// HyperbolicMLR: out[b,c] = -asinh( 2*sc_diff_a / ((1+diff_norm2)*|a_c|) )
// with px = <x_proj_b, p_c>, xa = <x_proj_b, a_c> via bf16 MFMA GEMMs.

#define EPSF 1e-15f
#define MAXN 0.99999f   // (1 - 1e-5) / sqrt(c), c = 1

constexpr int Bdim = 4096;
constexpr int Ddim = 1024;
constexpr int Cdim = 4096;

typedef __bf16 bf16x8 __attribute__((ext_vector_type(8)));
typedef float  f32x4  __attribute__((ext_vector_type(4)));
typedef unsigned short u16;

__device__ __forceinline__ u16 f2bf(float f) {
  __hip_bfloat16 h = __float2bfloat16(f);   // RNE
  return *reinterpret_cast<const u16*>(&h);
}

__device__ __forceinline__ void gl_lds16(const u16* g, u16* l) {
  __builtin_amdgcn_global_load_lds(
      (const __attribute__((address_space(1))) void*)g,
      (__attribute__((address_space(3))) void*)l, 16, 0, 0);
}

// ---------------- prep kernels ----------------

__global__ __launch_bounds__(256) void prep_x(const float* __restrict__ x,
                                              u16* __restrict__ xb,
                                              float* __restrict__ x2o) {
  const int b = blockIdx.x, t = threadIdx.x;
  float4 v = ((const float4*)(x + (size_t)b * Ddim))[t];
  float s = v.x * v.x + v.y * v.y + v.z * v.z + v.w * v.w;
  __shared__ float red[4];
#pragma unroll
  for (int o = 32; o > 0; o >>= 1) s += __shfl_down(s, o);
  if ((t & 63) == 0) red[t >> 6] = s;
  __syncthreads();
  s = red[0] + red[1] + red[2] + red[3];
  float norm  = sqrtf(s);
  float xn    = fmaxf(norm, EPSF);
  float scale = (xn > MAXN) ? (MAXN / xn) : 1.0f;
  if (t == 0) x2o[b] = s * scale * scale;
  ushort4 o4;
  o4.x = f2bf(v.x * scale); o4.y = f2bf(v.y * scale);
  o4.z = f2bf(v.z * scale); o4.w = f2bf(v.w * scale);
  ((ushort4*)(xb + (size_t)b * Ddim))[t] = o4;
}

__global__ __launch_bounds__(256) void prep_pa(const float* __restrict__ a,
                                               const float* __restrict__ p,
                                               u16* __restrict__ ab,
                                               u16* __restrict__ pbuf,
                                               float* __restrict__ p2o,
                                               float* __restrict__ pao,
                                               float* __restrict__ ano) {
  const int c = blockIdx.x, t = threadIdx.x;
  float4 av = ((const float4*)(a + (size_t)c * Ddim))[t];
  float4 pv = ((const float4*)(p + (size_t)c * Ddim))[t];
  float sp2 = pv.x * pv.x + pv.y * pv.y + pv.z * pv.z + pv.w * pv.w;
  float spa = pv.x * av.x + pv.y * av.y + pv.z * av.z + pv.w * av.w;
  float sa2 = av.x * av.x + av.y * av.y + av.z * av.z + av.w * av.w;
  __shared__ float red[12];
#pragma unroll
  for (int o = 32; o > 0; o >>= 1) {
    sp2 += __shfl_down(sp2, o);
    spa += __shfl_down(spa, o);
    sa2 += __shfl_down(sa2, o);
  }
  if ((t & 63) == 0) { int w = t >> 6; red[w] = sp2; red[4 + w] = spa; red[8 + w] = sa2; }
  __syncthreads();
  if (t == 0) {
    p2o[c] = red[0] + red[1] + red[2] + red[3];
    pao[c] = red[4] + red[5] + red[6] + red[7];
    ano[c] = sqrtf(red[8] + red[9] + red[10] + red[11]);
  }
  ushort4 oa, op;
  oa.x = f2bf(av.x); oa.y = f2bf(av.y); oa.z = f2bf(av.z); oa.w = f2bf(av.w);
  op.x = f2bf(pv.x); op.y = f2bf(pv.y); op.z = f2bf(pv.z); op.w = f2bf(pv.w);
  ((ushort4*)(ab   + (size_t)c * Ddim))[t] = oa;
  ((ushort4*)(pbuf + (size_t)c * Ddim))[t] = op;
}

// ---------------- fused dual-GEMM + epilogue ----------------
// 128x128 tile, BK=32, 4 waves (2x2 of 64x64), single-buffer m97-style loop.

__global__ __launch_bounds__(256) void gemm_ep(
    const u16* __restrict__ xb, const u16* __restrict__ pb,
    const u16* __restrict__ ab, const float* __restrict__ x2g,
    const float* __restrict__ p2g, const float* __restrict__ pag,
    const float* __restrict__ ang, float* __restrict__ out) {
  __shared__ u16 Xs[128 * 32];
  __shared__ u16 Ps[128 * 32];
  __shared__ u16 As[128 * 32];
  __shared__ float x2s[128], p2s[128], pas[128], ans[128];

  const int t = threadIdx.x;
  const int rowBase = blockIdx.y * 128;
  const int colBase = blockIdx.x * 128;

  if (t < 128) {
    x2s[t] = x2g[rowBase + t];
    p2s[t] = p2g[colBase + t];
    pas[t] = pag[colBase + t];
    ans[t] = ang[colBase + t];
  }

  const int lane = t & 63;
  const int wid  = t >> 6;
  const int wr   = wid >> 1;     // wave row 0..1
  const int wc   = wid & 1;      // wave col 0..1

  // staging: thread t covers 16B chunk t (rows 0..63) and chunk 256+t (rows 64..127)
  const int rx0 = t >> 2;
  const int kk  = (t & 3) * 8;
  const u16* xp0 = xb + (size_t)(rowBase + rx0) * Ddim + kk;
  const u16* xp1 = xp0 + 64 * Ddim;
  const u16* pp0 = pb + (size_t)(colBase + rx0) * Ddim + kk;
  const u16* pp1 = pp0 + 64 * Ddim;
  const u16* ap0 = ab + (size_t)(colBase + rx0) * Ddim + kk;
  const u16* ap1 = ap0 + 64 * Ddim;
  u16* lx0 = &Xs[t * 8]; u16* lx1 = &Xs[2048 + t * 8];
  u16* lp0 = &Ps[t * 8]; u16* lp1 = &Ps[2048 + t * 8];
  u16* la0 = &As[t * 8]; u16* la1 = &As[2048 + t * 8];

  // fragment LDS offsets (ushort units)
  const int abase = (wr * 64 + (lane & 15)) * 32 + (lane >> 4) * 8;
  const int bbase = (wc * 64 + (lane & 15)) * 32 + (lane >> 4) * 8;

  f32x4 accP[4][4], accA[4][4];
  const f32x4 zero = {0.f, 0.f, 0.f, 0.f};
#pragma unroll
  for (int m = 0; m < 4; ++m)
#pragma unroll
    for (int n = 0; n < 4; ++n) { accP[m][n] = zero; accA[m][n] = zero; }

  for (int kt = 0; kt < Ddim / 32; ++kt) {
    gl_lds16(xp0, lx0); gl_lds16(xp1, lx1);
    gl_lds16(pp0, lp0); gl_lds16(pp1, lp1);
    gl_lds16(ap0, la0); gl_lds16(ap1, la1);
    xp0 += 32; xp1 += 32; pp0 += 32; pp1 += 32; ap0 += 32; ap1 += 32;
    __syncthreads();   // drains vmcnt(0) then barrier

    bf16x8 av[4], bp[4], ba[4];
#pragma unroll
    for (int m = 0; m < 4; ++m) av[m] = *(const bf16x8*)&Xs[abase + m * 512];
#pragma unroll
    for (int n = 0; n < 4; ++n) {
      bp[n] = *(const bf16x8*)&Ps[bbase + n * 512];
      ba[n] = *(const bf16x8*)&As[bbase + n * 512];
    }
#pragma unroll
    for (int m = 0; m < 4; ++m)
#pragma unroll
      for (int n = 0; n < 4; ++n) {
        accP[m][n] = __builtin_amdgcn_mfma_f32_16x16x32_bf16(av[m], bp[n], accP[m][n], 0, 0, 0);
        accA[m][n] = __builtin_amdgcn_mfma_f32_16x16x32_bf16(av[m], ba[n], accA[m][n], 0, 0, 0);
      }
    __syncthreads();
  }

  // epilogue: C/D layout col = lane&15, row = (lane>>4)*4 + j
#pragma unroll
  for (int m = 0; m < 4; ++m) {
    const int rl0 = wr * 64 + m * 16 + (lane >> 4) * 4;
#pragma unroll
    for (int n = 0; n < 4; ++n) {
      const int cl  = wc * 64 + n * 16 + (lane & 15);
      const float p2c = p2s[cl], pac = pas[cl], anc = ans[cl];
      const float Bcc = 1.0f - p2c;
      f32x4 px4 = accP[m][n];
      f32x4 xa4 = accA[m][n];
#pragma unroll
      for (int j = 0; j < 4; ++j) {
        const float x2r = x2s[rl0 + j];
        const float px = px4[j];
        const float xa = xa4[j];
        const float Av  = 1.0f - 2.0f * px + x2r;
        const float den = fmaxf(1.0f - 2.0f * px + x2r * p2c, EPSF);
        const float dn2 = fmaxf((Av * Av * p2c + Bcc * Bcc * x2r - 2.0f * Av * Bcc * px) / (den * den), EPSF);
        const float sc  = (Bcc * xa - Av * pac) / den;
        const float dv  = fmaxf((1.0f + dn2) * anc, EPSF);   // always positive
        const float z   = (2.0f * sc) / dv;
        out[(size_t)(rowBase + rl0 + j) * Cdim + (colBase + cl)] = -asinhf(z);
      }
    }
  }
}

extern "C" void kernel_launch(void* const* d_in, const int* in_sizes, int n_in,
                              void* d_out, int out_size, void* d_ws, size_t ws_size,
                              hipStream_t stream) {
  const float* x = (const float*)d_in[0];
  const float* a = (const float*)d_in[1];
  const float* p = (const float*)d_in[2];
  float* out = (float*)d_out;

  char* ws = (char*)d_ws;
  u16* xb = (u16*)(ws);                                   // 8 MiB
  u16* pb = (u16*)(ws + (size_t)8 * 1024 * 1024);         // 8 MiB
  u16* ab = (u16*)(ws + (size_t)16 * 1024 * 1024);        // 8 MiB
  float* x2 = (float*)(ws + (size_t)24 * 1024 * 1024);    // 16 KiB
  float* p2 = x2 + Bdim;
  float* pa = p2 + Cdim;
  float* an = pa + Cdim;

  prep_x <<<Bdim, 256, 0, stream>>>(x, xb, x2);
  prep_pa<<<Cdim, 256, 0, stream>>>(a, p, ab, pb, p2, pa, an);
  gemm_ep<<<dim3(Cdim / 128, Bdim / 128), 256, 0, stream>>>(xb, pb, ab, x2, p2, pa, an, out);
}